// Round 4
// baseline (207.196 us; speedup 1.0000x reference)
//
#include <hip/hip_runtime.h>

// SOM loss, MI355X. Dims fixed: B=4096, D=1024, m=n=128, T=100.
// ws layout:
//   Xb   bf16[4096][1024]        @ 0
//   Wb   bf16[16384][1024]       @ 8388608
//   x2   f32[4096]               @ 41943040
//   w2   f32[16384]              @ 41959424
//   d2   bf16[4096][16384]       @ 42024960
//   pmin f32[4096][64]           @ 176242688
//   pidx i32[4096][64]           @ 178339840
//   lossb f32[4096]              @ 180453376

typedef __attribute__((ext_vector_type(8))) short short8;
typedef __attribute__((ext_vector_type(4))) float f32x4;
typedef unsigned short ushort_t;

#define B_ROWS 4096
#define DIM    1024
#define MN     16384
#define NJB    64

__device__ static inline ushort_t f32_to_bf16(float f) {
    unsigned u = __float_as_uint(f);
    u = (u + 0x7FFFu + ((u >> 16) & 1u)) >> 16;   // RTN-even
    return (ushort_t)u;
}
__device__ static inline float bf16_to_f32(ushort_t h) {
    return __uint_as_float(((unsigned)h) << 16);
}
__device__ static inline void gload_lds16(const void* g, void* l) {
    __builtin_amdgcn_global_load_lds(
        (const __attribute__((address_space(1))) unsigned*)g,
        (__attribute__((address_space(3))) unsigned*)l, 16, 0, 0);
}

// ---------- Kernel 1: f32 -> bf16 conversion + row sum-of-squares ----------
__global__ __launch_bounds__(256) void k_convert(
    const float* __restrict__ X, const float* __restrict__ W,
    ushort_t* __restrict__ Xb, ushort_t* __restrict__ Wb,
    float* __restrict__ x2, float* __restrict__ w2) {
    int row  = blockIdx.x * 4 + (threadIdx.x >> 6);
    int lane = threadIdx.x & 63;
    const float4* src;
    ushort4* dst;
    float* sq;
    if (row < B_ROWS) {
        src = (const float4*)(X + (size_t)row * DIM);
        dst = (ushort4*)(Xb + (size_t)row * DIM);
        sq  = x2 + row;
    } else {
        int r2 = row - B_ROWS;
        src = (const float4*)(W + (size_t)r2 * DIM);
        dst = (ushort4*)(Wb + (size_t)r2 * DIM);
        sq  = w2 + r2;
    }
    float s = 0.f;
    #pragma unroll
    for (int c = 0; c < 4; ++c) {
        float4 v = src[c * 64 + lane];
        s += v.x * v.x + v.y * v.y + v.z * v.z + v.w * v.w;
        ushort4 o = { f32_to_bf16(v.x), f32_to_bf16(v.y),
                      f32_to_bf16(v.z), f32_to_bf16(v.w) };
        dst[c * 64 + lane] = o;
    }
    #pragma unroll
    for (int d = 1; d < 64; d <<= 1) s += __shfl_xor(s, d);
    if (lane == 0) *sq = s;
}

// ---------- Kernel 2: 256x256 8-phase GEMM, 1-phase frag read-ahead ----------
// 512 thr = 8 waves (2M x 4N). Swapped MFMA operands (W as A, X as B):
// per-lane 4 consecutive d2 cols. One barrier per phase; frags for phase p+1
// issued during phase p (2 W reg-sets + 2 X reg-sets). vmcnt gates at g2/g6.
__global__ __launch_bounds__(512, 2) void k_gemm256(
    const ushort_t* __restrict__ Xb, const ushort_t* __restrict__ Wb,
    const float* __restrict__ x2, const float* __restrict__ w2,
    ushort_t* __restrict__ d2, float* __restrict__ pmin, int* __restrict__ pidx) {
    __shared__ __attribute__((aligned(1024))) unsigned char ldsb[131072];

    const int tid  = threadIdx.x;
    const int lane = tid & 63;
    const int w    = tid >> 6;
    const int wr   = w >> 2;      // 0..1  (X-row half)
    const int wc   = w & 3;       // 0..3  (W-col quarter)
    const int lc   = lane & 15;
    const int lr16 = lane >> 4;   // 0..3

    // XCD-bijective block swizzle (1024 % 8 == 0)
    const int bid = blockIdx.x;
    const int swz = (bid & 7) * 128 + (bid >> 3);
    const int tn  = swz >> 4;     // 0..63  W-tile
    const int tm  = swz & 15;     // 0..15  X-tile

    // ds_read tails (row r: byte col ^= ((r&7)<<4); r&7 == lc&7)
    const int smask = (lc & 7) << 4;
    const int tail0 = lc * 128 + ((lr16 * 16) ^ smask);        // kslice 0
    const int tail1 = lc * 128 + ((64 + lr16 * 16) ^ smask);   // kslice 1

    // staging: thread covers 16B at p = i*8192 + tid*16; inverse-swizzled source
    int rS[2], cS[2];
    #pragma unroll
    for (int i = 0; i < 2; ++i) {
        int p = i * 8192 + tid * 16;
        rS[i] = p >> 7;
        cS[i] = (((p & 127) ^ (((p >> 7) & 7) << 4)) >> 1);
    }
    const size_t aRow = (size_t)tm * 256;
    const size_t bRow = (size_t)tn * 256;

    #define STAGE(kt, d, ab, h) do {                                            \
        const ushort_t* _g = (ab) ? Wb : Xb;                                     \
        const size_t _rb = ((ab) ? bRow : aRow) + (h) * 128;                     \
        _Pragma("unroll")                                                        \
        for (int _i = 0; _i < 2; ++_i)                                           \
            gload_lds16(_g + (_rb + rS[_i]) * DIM + (kt) * 64 + cS[_i],          \
                        ldsb + (d) * 65536 + (ab) * 32768 + (h) * 16384          \
                             + _i * 8192 + tid * 16);                            \
    } while (0)

    short8 WA[4], WB[4], XA[4], XB[4];
    f32x4  acc[8][4];
    #pragma unroll
    for (int i = 0; i < 8; ++i)
        #pragma unroll
        for (int j = 0; j < 4; ++j) acc[i][j] = (f32x4)0.f;

    #define LDW(d, DST, TAIL) do { _Pragma("unroll")                             \
        for (int _n = 0; _n < 4; ++_n)                                           \
            DST[_n] = *(const short8*)(ldsb + (d) * 65536 + 32768 + wc * 8192    \
                                + _n * 2048 + (TAIL)); } while (0)
    #define LDX(d, DST, I0, TAIL) do { _Pragma("unroll")                         \
        for (int _m = 0; _m < 4; ++_m)                                           \
            DST[_m] = *(const short8*)(ldsb + (d) * 65536 + wr * 16384           \
                                + ((I0) + _m) * 2048 + (TAIL)); } while (0)
    #define PH(WFV, XFV, IB) do {                                                \
        __builtin_amdgcn_s_setprio(1);                                           \
        _Pragma("unroll")                                                        \
        for (int _m = 0; _m < 4; ++_m) { _Pragma("unroll")                       \
            for (int _n = 0; _n < 4; ++_n)                                       \
                acc[(IB) + _m][_n] = __builtin_amdgcn_mfma_f32_16x16x32_bf16(    \
                    WFV[_n], XFV[_m], acc[(IB) + _m][_n], 0, 0, 0); }            \
        __builtin_amdgcn_s_setprio(0); } while (0)
    #define BAR() do { __builtin_amdgcn_sched_barrier(0);                        \
        __builtin_amdgcn_s_barrier();                                            \
        __builtin_amdgcn_sched_barrier(0); } while (0)
    #define WLG(n) do { asm volatile("s_waitcnt lgkmcnt(" #n ")" ::: "memory");  \
        __builtin_amdgcn_sched_barrier(0); } while (0)
    #define GATE() do { __builtin_amdgcn_sched_barrier(0);                       \
        asm volatile("s_waitcnt vmcnt(0)" ::: "memory"); } while (0)

    // ---- prologue: T0 -> dbuf0; pre-issue frags for g0 ----
    STAGE(0, 0, 0, 0); STAGE(0, 0, 0, 1); STAGE(0, 0, 1, 0); STAGE(0, 0, 1, 1);
    GATE();
    BAR();
    LDW(0, WA, tail0); LDX(0, XA, 0, tail0);   // 8 reads in flight

    for (int it = 0; it < 8; ++it) {
        const int  T1  = 2 * it + 1;   // -> dbuf1 (read g4..g7)
        const int  T0n = 2 * it + 2;   // -> dbuf0 (read next iter)
        const bool pf  = (it < 7);
        // g0: issue XB(d0 mi4-7 ks0); drain WA,XA; stage T1 A
        LDX(0, XB, 4, tail0);
        WLG(4);
        STAGE(T1, 1, 0, 0); STAGE(T1, 1, 0, 1);
        PH(WA, XA, 0);
        BAR();
        // g1: issue XA(d0 ks1), WB(d0 ks1); drain XB; stage T1 B
        LDX(0, XA, 0, tail1); LDW(0, WB, tail1);
        WLG(8);
        STAGE(T1, 1, 1, 0); STAGE(T1, 1, 1, 1);
        PH(WA, XB, 4);
        BAR();
        // g2: issue XB(d0 mi4-7 ks1); drain XA,WB; gate dbuf1 after MFMA
        LDX(0, XB, 4, tail1);
        WLG(4);
        PH(WB, XA, 0);
        GATE();
        BAR();
        // g3: issue XA(d1 ks0), WA(d1 ks0); drain XB
        LDX(1, XA, 0, tail0); LDW(1, WA, tail0);
        WLG(8);
        PH(WB, XB, 4);
        BAR();
        // g4: issue XB(d1 mi4-7 ks0); drain XA,WA; stage T0n A
        LDX(1, XB, 4, tail0);
        WLG(4);
        if (pf) { STAGE(T0n, 0, 0, 0); STAGE(T0n, 0, 0, 1); }
        PH(WA, XA, 0);
        BAR();
        // g5: issue XA(d1 ks1), WB(d1 ks1); drain XB; stage T0n B
        LDX(1, XA, 0, tail1); LDW(1, WB, tail1);
        WLG(8);
        if (pf) { STAGE(T0n, 0, 1, 0); STAGE(T0n, 0, 1, 1); }
        PH(WA, XB, 4);
        BAR();
        // g6: issue XB(d1 mi4-7 ks1); drain XA,WB; gate dbuf0-next
        LDX(1, XB, 4, tail1);
        WLG(4);
        PH(WB, XA, 0);
        if (pf) GATE();
        BAR();
        // g7: issue XA(d0-next ks0), WA(d0-next ks0); drain XB
        if (pf) { LDX(0, XA, 0, tail0); LDW(0, WA, tail0); WLG(8); }
        else    { WLG(0); }
        PH(WB, XB, 4);
        BAR();
    }

    // ---- epilogue: d2 = x2 - 2*dot + w2, LDS-transposed coalesced stores ----
    // per-wave 16KB LDS region: [i:8][lc:16][64 cols bf16], col-byte XOR ((lc&7)<<4)
    unsigned char* wls = ldsb + w * 16384;
    const int colw = tn * 256 + wc * 64;
    const int rowbase = tm * 256 + wr * 128;
    float4 w2q[4];
    #pragma unroll
    for (int ni = 0; ni < 4; ++ni)
        w2q[ni] = *(const float4*)(w2 + colw + ni * 16 + lr16 * 4);

    float mnA[8]; int ixA[8];
    #pragma unroll
    for (int i = 0; i < 8; ++i) {
        const int row = rowbase + i * 16 + lc;
        const float xx = x2[row];
        float mn = __builtin_inff(); int ix = 0x7fffffff;
        #pragma unroll
        for (int ni = 0; ni < 4; ++ni) {
            float dv[4];
            ushort4 st;
            #pragma unroll
            for (int rg = 0; rg < 4; ++rg) {
                dv[rg] = xx - 2.f * acc[i][ni][rg] + w2q[ni][rg];
                st[rg] = (unsigned short)f32_to_bf16(dv[rg]);
            }
            *(ushort4*)(wls + i * 2048 + lc * 128
                        + ((ni * 32 + lr16 * 8) ^ smask)) = st;
            #pragma unroll
            for (int rg = 0; rg < 4; ++rg) {
                const int cand = colw + ni * 16 + lr16 * 4 + rg;
                if (dv[rg] < mn || (dv[rg] == mn && cand < ix)) { mn = dv[rg]; ix = cand; }
            }
        }
        #pragma unroll
        for (int d = 16; d < 64; d <<= 1) {
            float om = __shfl_xor(mn, d);
            int   oi = __shfl_xor(ix, d);
            if (om < mn || (om == mn && oi < ix)) { mn = om; ix = oi; }
        }
        mnA[i] = mn; ixA[i] = ix;
    }
    // read back transposed, fully-coalesced 16B stores (8 lanes = 128B/row)
    #pragma unroll
    for (int j = 0; j < 16; ++j) {
        const int rl  = j * 8 + (lane >> 3);      // row_local 0..127
        const int ii  = rl >> 4, lcr = rl & 15;
        const int cb  = (lane & 7) * 16;          // byte col in 128B row
        short8 v = *(const short8*)(wls + ii * 2048 + lcr * 128
                                    + (cb ^ ((lcr & 7) << 4)));
        *(short8*)((char*)(d2 + (size_t)(rowbase + rl) * MN + colw) + cb) = v;
    }
    __syncthreads();
    // per-row argmin partials across the 4 N-waves
    float* smin = (float*)ldsb;            // [256][4]
    int*   sidx = (int*)(ldsb + 4096);     // [256][4]
    if (lane < 16) {
        #pragma unroll
        for (int i = 0; i < 8; ++i) {
            const int rloc = wr * 128 + i * 16 + lane;
            smin[rloc * 4 + wc] = mnA[i];
            sidx[rloc * 4 + wc] = ixA[i];
        }
    }
    __syncthreads();
    if (tid < 256) {
        float mn = smin[tid * 4]; int ix = sidx[tid * 4];
        #pragma unroll
        for (int c = 1; c < 4; ++c) {
            float om = smin[tid * 4 + c]; int oi = sidx[tid * 4 + c];
            if (om < mn || (om == mn && oi < ix)) { mn = om; ix = oi; }
        }
        const int row = tm * 256 + tid;
        pmin[(size_t)row * NJB + tn] = mn;
        pidx[(size_t)row * NJB + tn] = ix;
    }
    #undef STAGE
    #undef LDW
    #undef LDX
    #undef PH
    #undef BAR
    #undef WLG
    #undef GATE
}

// ---------- Kernel 3: fused argmin-finish + influence-weighted row sum ----------
__global__ __launch_bounds__(256) void k_loss(
    const ushort_t* __restrict__ d2, const float* __restrict__ pmin,
    const int* __restrict__ pidx, float* __restrict__ lossb) {
    __shared__ float etab[255];
    __shared__ float red[4];
    __shared__ int bmu_s;
    int t = threadIdx.x;
    if (t < 255) etab[t] = __expf(-(float)(t * t) * 1e-4f);  // exp(-r^2/T^2), T=100
    int row = blockIdx.x;
    if (t < 64) {
        float m0 = pmin[(size_t)row * NJB + t];
        int   i0 = pidx[(size_t)row * NJB + t];
        #pragma unroll
        for (int d = 1; d < 64; d <<= 1) {
            float om = __shfl_xor(m0, d);
            int   oi = __shfl_xor(i0, d);
            if (om < m0 || (om == m0 && oi < i0)) { m0 = om; i0 = oi; }
        }
        if (t == 0) bmu_s = i0;
    }
    __syncthreads();
    int bl = bmu_s;
    int bi = bl >> 7, bj = bl & 127;
    const ushort_t* dr = d2 + (size_t)row * MN;
    float s = 0.f;
    #pragma unroll
    for (int c = 0; c < 8; ++c) {
        int j = c * 2048 + t * 8;
        short8 v = *(const short8*)&dr[j];
        int di = abs((j >> 7) - bi);
        int jc = j & 127;
        #pragma unroll
        for (int u = 0; u < 8; ++u) {
            int mh = di + abs(jc + u - bj);
            s += bf16_to_f32((ushort_t)v[u]) * etab[mh];
        }
    }
    #pragma unroll
    for (int d = 1; d < 64; d <<= 1) s += __shfl_xor(s, d);
    if ((t & 63) == 0) red[t >> 6] = s;
    __syncthreads();
    if (t == 0) lossb[row] = red[0] + red[1] + red[2] + red[3];
}

// ---------- Kernel 4: final deterministic reduce ----------
__global__ __launch_bounds__(256) void k_final(
    const float* __restrict__ lossb, float* __restrict__ out) {
    __shared__ float red[4];
    int t = threadIdx.x;
    float s = 0.f;
    #pragma unroll
    for (int k = 0; k < 16; ++k) s += lossb[t + k * 256];
    #pragma unroll
    for (int d = 1; d < 64; d <<= 1) s += __shfl_xor(s, d);
    if ((t & 63) == 0) red[t >> 6] = s;
    __syncthreads();
    if (t == 0) out[0] = (red[0] + red[1] + red[2] + red[3]) * (1.0f / 128.0f);
}

extern "C" void kernel_launch(void* const* d_in, const int* in_sizes, int n_in,
                              void* d_out, int out_size, void* d_ws, size_t ws_size,
                              hipStream_t stream) {
    const float* X = (const float*)d_in[0];
    const float* W = (const float*)d_in[1];
    unsigned char* ws = (unsigned char*)d_ws;
    ushort_t* Xb   = (ushort_t*)(ws);
    ushort_t* Wb   = (ushort_t*)(ws + 8388608);
    float*    x2   = (float*)(ws + 41943040);
    float*    w2   = (float*)(ws + 41959424);
    ushort_t* d2   = (ushort_t*)(ws + 42024960);
    float*    pmin = (float*)(ws + 176242688);
    int*      pidx = (int*)(ws + 178339840);
    float*    lossb= (float*)(ws + 180453376);

    k_convert<<<5120, 256, 0, stream>>>(X, W, Xb, Wb, x2, w2);
    k_gemm256<<<1024, 512, 0, stream>>>(Xb, Wb, x2, w2, d2, pmin, pidx);
    k_loss<<<4096, 256, 0, stream>>>(d2, pmin, pidx, lossb);
    k_final<<<1, 256, 0, stream>>>(lossb, (float*)d_out);
}

// Round 5
// 204.191 us; speedup vs baseline: 1.0147x; 1.0147x over previous
//
#include <hip/hip_runtime.h>

// SOM loss, MI355X. Dims fixed: B=4096, D=1024, m=n=128, T=100.
// ws layout:
//   Xb   bf16[4096][1024]        @ 0
//   Wb   bf16[16384][1024]       @ 8388608
//   x2   f32[4096]               @ 41943040
//   w2   f32[16384]              @ 41959424
//   d2   bf16[4096][16384]       @ 42024960
//   pmin f32[4096][64]           @ 176242688
//   pidx i32[4096][64]           @ 178339840
//   lossb f32[4096]              @ 180453376

typedef __attribute__((ext_vector_type(8))) short short8;
typedef __attribute__((ext_vector_type(4))) float f32x4;
typedef unsigned short ushort_t;

#define B_ROWS 4096
#define DIM    1024
#define MN     16384
#define NJB    64

__device__ static inline ushort_t f32_to_bf16(float f) {
    unsigned u = __float_as_uint(f);
    u = (u + 0x7FFFu + ((u >> 16) & 1u)) >> 16;   // RTN-even
    return (ushort_t)u;
}
__device__ static inline float bf16_to_f32(ushort_t h) {
    return __uint_as_float(((unsigned)h) << 16);
}
__device__ static inline void gload_lds16(const void* g, void* l) {
    __builtin_amdgcn_global_load_lds(
        (const __attribute__((address_space(1))) unsigned*)g,
        (__attribute__((address_space(3))) unsigned*)l, 16, 0, 0);
}

// ---------- Kernel 1: f32 -> bf16 conversion + row sum-of-squares ----------
__global__ __launch_bounds__(256) void k_convert(
    const float* __restrict__ X, const float* __restrict__ W,
    ushort_t* __restrict__ Xb, ushort_t* __restrict__ Wb,
    float* __restrict__ x2, float* __restrict__ w2) {
    int row  = blockIdx.x * 4 + (threadIdx.x >> 6);
    int lane = threadIdx.x & 63;
    const float4* src;
    ushort4* dst;
    float* sq;
    if (row < B_ROWS) {
        src = (const float4*)(X + (size_t)row * DIM);
        dst = (ushort4*)(Xb + (size_t)row * DIM);
        sq  = x2 + row;
    } else {
        int r2 = row - B_ROWS;
        src = (const float4*)(W + (size_t)r2 * DIM);
        dst = (ushort4*)(Wb + (size_t)r2 * DIM);
        sq  = w2 + r2;
    }
    float s = 0.f;
    #pragma unroll
    for (int c = 0; c < 4; ++c) {
        float4 v = src[c * 64 + lane];
        s += v.x * v.x + v.y * v.y + v.z * v.z + v.w * v.w;
        ushort4 o = { f32_to_bf16(v.x), f32_to_bf16(v.y),
                      f32_to_bf16(v.z), f32_to_bf16(v.w) };
        dst[c * 64 + lane] = o;
    }
    #pragma unroll
    for (int d = 1; d < 64; d <<= 1) s += __shfl_xor(s, d);
    if (lane == 0) *sq = s;
}

// ---------- Kernel 2: 256x256 GEMM, 4-barrier iteration + bulk staging ----------
// 512 thr = 8 waves (2M x 4N). Swapped MFMA operands (W as A, X as B).
// Barriers ONLY at buffer transitions: GATE->BAR1 (dbuf readable),
// WLG->BAR2 (reads drained) -> bulk stage. Per-wave counted lgkm FIFO
// pipelines ds_reads under MFMA inside the barrier-free regions.
__global__ __launch_bounds__(512, 2) void k_gemm256(
    const ushort_t* __restrict__ Xb, const ushort_t* __restrict__ Wb,
    const float* __restrict__ x2, const float* __restrict__ w2,
    ushort_t* __restrict__ d2, float* __restrict__ pmin, int* __restrict__ pidx) {
    __shared__ __attribute__((aligned(1024))) unsigned char ldsb[131072];

    const int tid  = threadIdx.x;
    const int lane = tid & 63;
    const int w    = tid >> 6;
    const int wr   = w >> 2;      // 0..1  (X-row half)
    const int wc   = w & 3;       // 0..3  (W-col quarter)
    const int lc   = lane & 15;
    const int lr16 = lane >> 4;   // 0..3

    // XCD-bijective block swizzle (1024 % 8 == 0)
    const int bid = blockIdx.x;
    const int swz = (bid & 7) * 128 + (bid >> 3);
    const int tn  = swz >> 4;     // 0..63  W-tile
    const int tm  = swz & 15;     // 0..15  X-tile

    // ds_read tails (row r: byte col ^= ((r&7)<<4); r&7 == lc&7)
    const int smask = (lc & 7) << 4;
    const int tail0 = lc * 128 + ((lr16 * 16) ^ smask);        // kslice 0
    const int tail1 = lc * 128 + ((64 + lr16 * 16) ^ smask);   // kslice 1

    // staging: thread covers 16B at p = i*8192 + tid*16; inverse-swizzled source
    int rS[2], cS[2];
    #pragma unroll
    for (int i = 0; i < 2; ++i) {
        int p = i * 8192 + tid * 16;
        rS[i] = p >> 7;
        cS[i] = (((p & 127) ^ (((p >> 7) & 7) << 4)) >> 1);
    }
    const size_t aRow = (size_t)tm * 256;
    const size_t bRow = (size_t)tn * 256;

    #define STAGE(kt, d, ab, h) do {                                            \
        const ushort_t* _g = (ab) ? Wb : Xb;                                     \
        const size_t _rb = ((ab) ? bRow : aRow) + (h) * 128;                     \
        _Pragma("unroll")                                                        \
        for (int _i = 0; _i < 2; ++_i)                                           \
            gload_lds16(_g + (_rb + rS[_i]) * DIM + (kt) * 64 + cS[_i],          \
                        ldsb + (d) * 65536 + (ab) * 32768 + (h) * 16384          \
                             + _i * 8192 + tid * 16);                            \
    } while (0)

    short8 WA[4], WB[4], XA[4], XB[4];
    f32x4  acc[8][4];
    #pragma unroll
    for (int i = 0; i < 8; ++i)
        #pragma unroll
        for (int j = 0; j < 4; ++j) acc[i][j] = (f32x4)0.f;

    #define LDW(d, DST, TAIL) do { _Pragma("unroll")                             \
        for (int _n = 0; _n < 4; ++_n)                                           \
            DST[_n] = *(const short8*)(ldsb + (d) * 65536 + 32768 + wc * 8192    \
                                + _n * 2048 + (TAIL)); } while (0)
    #define LDX(d, DST, I0, TAIL) do { _Pragma("unroll")                         \
        for (int _m = 0; _m < 4; ++_m)                                           \
            DST[_m] = *(const short8*)(ldsb + (d) * 65536 + wr * 16384           \
                                + ((I0) + _m) * 2048 + (TAIL)); } while (0)
    #define PH(WFV, XFV, IB) do {                                                \
        __builtin_amdgcn_s_setprio(1);                                           \
        _Pragma("unroll")                                                        \
        for (int _m = 0; _m < 4; ++_m) { _Pragma("unroll")                       \
            for (int _n = 0; _n < 4; ++_n)                                       \
                acc[(IB) + _m][_n] = __builtin_amdgcn_mfma_f32_16x16x32_bf16(    \
                    WFV[_n], XFV[_m], acc[(IB) + _m][_n], 0, 0, 0); }            \
        __builtin_amdgcn_s_setprio(0); } while (0)
    #define BAR() __builtin_amdgcn_s_barrier()
    #define WLG(n) do { asm volatile("s_waitcnt lgkmcnt(" #n ")" ::: "memory");  \
        __builtin_amdgcn_sched_barrier(0); } while (0)
    #define GATE() asm volatile("s_waitcnt vmcnt(0)" ::: "memory")

    // ---- prologue: T0 -> dbuf0, T1 -> dbuf1 (T1 stays in flight) ----
    STAGE(0, 0, 0, 0); STAGE(0, 0, 0, 1); STAGE(0, 0, 1, 0); STAGE(0, 0, 1, 1);
    STAGE(1, 1, 0, 0); STAGE(1, 1, 0, 1); STAGE(1, 1, 1, 0); STAGE(1, 1, 1, 1);
    asm volatile("s_waitcnt vmcnt(8)" ::: "memory");   // T0 landed, T1 counted
    __builtin_amdgcn_sched_barrier(0);
    BAR();
    LDW(0, WA, tail0); LDX(0, XA, 0, tail0);   // 8 reads in flight

    for (int it = 0; it < 8; ++it) {
        const int  T0n = 2 * it + 2;   // -> dbuf0 (read next iter)
        const int  T1n = 2 * it + 3;   // -> dbuf1 (read next iter)
        const bool pf  = (it < 7);
        // ---- dbuf0 compute: 3 free phases ----
        LDX(0, XB, 4, tail0); WLG(4); PH(WA, XA, 0);
        LDX(0, XA, 0, tail1); LDW(0, WB, tail1); WLG(8); PH(WA, XB, 4);
        LDX(0, XB, 4, tail1); WLG(4); PH(WB, XA, 0);
        GATE();                               // T1 landed (4 phases old)
        __builtin_amdgcn_sched_barrier(0);
        BAR();                                // BAR1: dbuf1 readable
        LDX(1, XA, 0, tail0); LDW(1, WA, tail0); WLG(8);
        BAR();                                // BAR2: all dbuf0 reads drained
        if (pf) { STAGE(T0n, 0, 0, 0); STAGE(T0n, 0, 0, 1);
                  STAGE(T0n, 0, 1, 0); STAGE(T0n, 0, 1, 1); }
        PH(WB, XB, 4);
        // ---- dbuf1 compute: 3 free phases ----
        LDX(1, XB, 4, tail0); WLG(4); PH(WA, XA, 0);
        LDX(1, XA, 0, tail1); LDW(1, WB, tail1); WLG(8); PH(WA, XB, 4);
        LDX(1, XB, 4, tail1); WLG(4); PH(WB, XA, 0);
        if (pf) GATE();                       // T0n landed (3 phases old)
        __builtin_amdgcn_sched_barrier(0);
        BAR();                                // BAR3: dbuf0 readable
        if (pf) { LDX(0, XA, 0, tail0); LDW(0, WA, tail0); WLG(8); }
        else    { WLG(0); }
        BAR();                                // BAR4: all dbuf1 reads drained
        if (pf) { STAGE(T1n, 1, 0, 0); STAGE(T1n, 1, 0, 1);
                  STAGE(T1n, 1, 1, 0); STAGE(T1n, 1, 1, 1); }
        PH(WB, XB, 4);
    }
    BAR();   // all frag reads drained everywhere before LDS reuse

    // ---- epilogue: d2 = x2 - 2*dot + w2, LDS-transposed coalesced stores ----
    // per-wave 16KB LDS region: [i:8][lc:16][64 cols bf16], col-byte XOR ((lc&7)<<4)
    unsigned char* wls = ldsb + w * 16384;
    const int colw = tn * 256 + wc * 64;
    const int rowbase = tm * 256 + wr * 128;
    float4 w2q[4];
    #pragma unroll
    for (int ni = 0; ni < 4; ++ni)
        w2q[ni] = *(const float4*)(w2 + colw + ni * 16 + lr16 * 4);

    float mnA[8]; int ixA[8];
    #pragma unroll
    for (int i = 0; i < 8; ++i) {
        const int row = rowbase + i * 16 + lc;
        const float xx = x2[row];
        float mn = __builtin_inff(); int ix = 0x7fffffff;
        #pragma unroll
        for (int ni = 0; ni < 4; ++ni) {
            float dv[4];
            ushort4 st;
            #pragma unroll
            for (int rg = 0; rg < 4; ++rg) {
                dv[rg] = xx - 2.f * acc[i][ni][rg] + w2q[ni][rg];
                st[rg] = (unsigned short)f32_to_bf16(dv[rg]);
            }
            *(ushort4*)(wls + i * 2048 + lc * 128
                        + ((ni * 32 + lr16 * 8) ^ smask)) = st;
            #pragma unroll
            for (int rg = 0; rg < 4; ++rg) {
                const int cand = colw + ni * 16 + lr16 * 4 + rg;
                if (dv[rg] < mn || (dv[rg] == mn && cand < ix)) { mn = dv[rg]; ix = cand; }
            }
        }
        #pragma unroll
        for (int d = 16; d < 64; d <<= 1) {
            float om = __shfl_xor(mn, d);
            int   oi = __shfl_xor(ix, d);
            if (om < mn || (om == mn && oi < ix)) { mn = om; ix = oi; }
        }
        mnA[i] = mn; ixA[i] = ix;
    }
    // read back transposed, fully-coalesced 16B stores (8 lanes = 128B/row)
    #pragma unroll
    for (int j = 0; j < 16; ++j) {
        const int rl  = j * 8 + (lane >> 3);      // row_local 0..127
        const int ii  = rl >> 4, lcr = rl & 15;
        const int cb  = (lane & 7) * 16;          // byte col in 128B row
        short8 v = *(const short8*)(wls + ii * 2048 + lcr * 128
                                    + (cb ^ ((lcr & 7) << 4)));
        *(short8*)((char*)(d2 + (size_t)(rowbase + rl) * MN + colw) + cb) = v;
    }
    __syncthreads();
    // per-row argmin partials across the 4 N-waves
    float* smin = (float*)ldsb;            // [256][4]
    int*   sidx = (int*)(ldsb + 4096);     // [256][4]
    if (lane < 16) {
        #pragma unroll
        for (int i = 0; i < 8; ++i) {
            const int rloc = wr * 128 + i * 16 + lane;
            smin[rloc * 4 + wc] = mnA[i];
            sidx[rloc * 4 + wc] = ixA[i];
        }
    }
    __syncthreads();
    if (tid < 256) {
        float mn = smin[tid * 4]; int ix = sidx[tid * 4];
        #pragma unroll
        for (int c = 1; c < 4; ++c) {
            float om = smin[tid * 4 + c]; int oi = sidx[tid * 4 + c];
            if (om < mn || (om == mn && oi < ix)) { mn = om; ix = oi; }
        }
        const int row = tm * 256 + tid;
        pmin[(size_t)row * NJB + tn] = mn;
        pidx[(size_t)row * NJB + tn] = ix;
    }
    #undef STAGE
    #undef LDW
    #undef LDX
    #undef PH
    #undef BAR
    #undef WLG
    #undef GATE
}

// ---------- Kernel 3: fused argmin-finish + influence-weighted row sum ----------
__global__ __launch_bounds__(256) void k_loss(
    const ushort_t* __restrict__ d2, const float* __restrict__ pmin,
    const int* __restrict__ pidx, float* __restrict__ lossb) {
    __shared__ float etab[255];
    __shared__ float red[4];
    __shared__ int bmu_s;
    int t = threadIdx.x;
    if (t < 255) etab[t] = __expf(-(float)(t * t) * 1e-4f);  // exp(-r^2/T^2), T=100
    int row = blockIdx.x;
    if (t < 64) {
        float m0 = pmin[(size_t)row * NJB + t];
        int   i0 = pidx[(size_t)row * NJB + t];
        #pragma unroll
        for (int d = 1; d < 64; d <<= 1) {
            float om = __shfl_xor(m0, d);
            int   oi = __shfl_xor(i0, d);
            if (om < m0 || (om == m0 && oi < i0)) { m0 = om; i0 = oi; }
        }
        if (t == 0) bmu_s = i0;
    }
    __syncthreads();
    int bl = bmu_s;
    int bi = bl >> 7, bj = bl & 127;
    const ushort_t* dr = d2 + (size_t)row * MN;
    float s = 0.f;
    #pragma unroll
    for (int c = 0; c < 8; ++c) {
        int j = c * 2048 + t * 8;
        short8 v = *(const short8*)&dr[j];
        int di = abs((j >> 7) - bi);
        int jc = j & 127;
        #pragma unroll
        for (int u = 0; u < 8; ++u) {
            int mh = di + abs(jc + u - bj);
            s += bf16_to_f32((ushort_t)v[u]) * etab[mh];
        }
    }
    #pragma unroll
    for (int d = 1; d < 64; d <<= 1) s += __shfl_xor(s, d);
    if ((t & 63) == 0) red[t >> 6] = s;
    __syncthreads();
    if (t == 0) lossb[row] = red[0] + red[1] + red[2] + red[3];
}

// ---------- Kernel 4: final deterministic reduce ----------
__global__ __launch_bounds__(256) void k_final(
    const float* __restrict__ lossb, float* __restrict__ out) {
    __shared__ float red[4];
    int t = threadIdx.x;
    float s = 0.f;
    #pragma unroll
    for (int k = 0; k < 16; ++k) s += lossb[t + k * 256];
    #pragma unroll
    for (int d = 1; d < 64; d <<= 1) s += __shfl_xor(s, d);
    if ((t & 63) == 0) red[t >> 6] = s;
    __syncthreads();
    if (t == 0) out[0] = (red[0] + red[1] + red[2] + red[3]) * (1.0f / 128.0f);
}

extern "C" void kernel_launch(void* const* d_in, const int* in_sizes, int n_in,
                              void* d_out, int out_size, void* d_ws, size_t ws_size,
                              hipStream_t stream) {
    const float* X = (const float*)d_in[0];
    const float* W = (const float*)d_in[1];
    unsigned char* ws = (unsigned char*)d_ws;
    ushort_t* Xb   = (ushort_t*)(ws);
    ushort_t* Wb   = (ushort_t*)(ws + 8388608);
    float*    x2   = (float*)(ws + 41943040);
    float*    w2   = (float*)(ws + 41959424);
    ushort_t* d2   = (ushort_t*)(ws + 42024960);
    float*    pmin = (float*)(ws + 176242688);
    int*      pidx = (int*)(ws + 178339840);
    float*    lossb= (float*)(ws + 180453376);

    k_convert<<<5120, 256, 0, stream>>>(X, W, Xb, Wb, x2, w2);
    k_gemm256<<<1024, 512, 0, stream>>>(Xb, Wb, x2, w2, d2, pmin, pidx);
    k_loss<<<4096, 256, 0, stream>>>(d2, pmin, pidx, lossb);
    k_final<<<1, 256, 0, stream>>>(lossb, (float*)d_out);
}